// Round 1
// baseline (401.163 us; speedup 1.0000x reference)
//
#include <hip/hip_runtime.h>

// UncertaintyDynamicQAgent: 1024-step sequential scan, 8192 independent sessions.
// One thread per session. sel_L/sel_R are one-hot -> all reductions collapse to
// table lookups selected by (chose_left, outcome). Latency-bound recurrence:
// wall time ~ per-step critical path (incl. smooth_clamp exp/log) * 1024.

#define N_TRIALS 1024
#define CH 16                       // steps per chunk
#define NC (N_TRIALS / CH)          // 64 chunks
#define F4_IN (CH * 3 / 4)          // 12 float4 input per chunk
#define F4_OUT (CH * 2 / 4)         // 8 float4 output per chunk

struct Tables {
    float k0, k1, k2, k3;
    float a00, a01, a02, a03;
    float ga0, ga1, ga2, ga3;
    float gl0, gl1, gl2, gl3;
};

// smooth_clamp(x, 0, 1) with beta = 100, matching JAX:
// where(x<0.5, sp(x), 1-sp(1-x)),  sp(z) = softplus(100 z)/100
// softplus(t) = max(t,0) + log1p(exp(-|t|))
__device__ __forceinline__ float smooth_clamp01(float x) {
    const bool low = x < 0.5f;
    const float y  = low ? x : (1.0f - x);
    const float t  = 100.0f * y;
    const float e  = __expf(-fabsf(t));       // v_exp_f32 path
    const float l  = __logf(1.0f + e);        // v_log_f32 path; 1+e in (1,2]
    const float sp = (fmaxf(t, 0.0f) + l) * 0.01f;
    return low ? sp : (1.0f - sp);
}

// Extract float i from a register-resident float4 array (i constant after unroll).
__device__ __forceinline__ float getf(const float4 (&b)[F4_IN], int i) {
    const float4 v = b[i >> 2];
    switch (i & 3) {
        case 0: return v.x;
        case 1: return v.y;
        case 2: return v.z;
        default: return v.w;
    }
}

// One scan step. jL = 3 - o - 2*cl, jR = jL ^ 2.
//   a = (jL & 1) = (o == 0);  b = (jL >> 1) = (cl == 0)
__device__ __forceinline__ void step(bool first, float cl, float o,
                                     float& Q0, float& Q1, float& l0, float& l1,
                                     float& al, const Tables& tb) {
    const bool b = cl < 0.5f;   // chose right
    const bool a = o  < 0.5f;   // no reward

    const float k_lo  = a ? tb.k1  : tb.k0;
    const float k_hi  = a ? tb.k3  : tb.k2;
    const float kL    = b ? k_hi   : k_lo;    // k_vals[jL]
    const float kR    = b ? k_lo   : k_hi;    // k_vals[jR]
    const float gl_lo = a ? tb.gl1 : tb.gl0;
    const float gl_hi = a ? tb.gl3 : tb.gl2;
    const float glL   = b ? gl_hi  : gl_lo;   // gamma_lams[jL]
    const float glR   = b ? gl_lo  : gl_hi;   // gamma_lams[jR]
    const float ga    = b ? (a ? tb.ga3 : tb.ga2) : (a ? tb.ga1 : tb.ga0); // gamma_alphas[jL]
    const float a0i   = a ? tb.a01 : tb.a00;  // alpha0s[jL & 1]

    const float dL    = kL - Q0;              // diffs_L[jL]
    const float dR    = kR - Q1;              // diffs_R[jR]
    const float lamdL = fabsf(dL) - l0;       // lamd_L[jL]
    const float lamdR = fabsf(dR) - l1;       // lamd_R[jR]

    float alpha_new;
    if (first) {
        // t==0: alpha_new = alpha0s[jL]
        alpha_new = b ? (a ? tb.a03 : tb.a02) : (a ? tb.a01 : tb.a00);
    } else {
        const float lamd_c = b ? lamdR : lamdL;
        alpha_new = smooth_clamp01(fmaf(ga, (a0i + lamd_c) - al, al));
    }

    const float nl0 = smooth_clamp01(fmaf(glL, lamdL, l0));
    const float nl1 = smooth_clamp01(fmaf(glR, lamdR, l1));
    const float nQ0 = fmaf(alpha_new * (1.0f - l0), dL, Q0);
    const float nQ1 = fmaf(alpha_new * (1.0f - l1), dR, Q1);

    Q0 = nQ0; Q1 = nQ1; l0 = nl0; l1 = nl1; al = alpha_new;
}

__device__ __forceinline__ void run_chunk(bool first_chunk,
                                          const float4 (&buf)[F4_IN],
                                          float4* __restrict__ outp,
                                          float& Q0, float& Q1, float& l0,
                                          float& l1, float& al,
                                          const Tables& tb) {
#pragma unroll
    for (int u = 0; u < CH; u += 2) {
        const float cl0 = getf(buf, 3 * u + 0);
        const float o0  = getf(buf, 3 * u + 2);
        if (u == 0) step(first_chunk, cl0, o0, Q0, Q1, l0, l1, al, tb);
        else        step(false,       cl0, o0, Q0, Q1, l0, l1, al, tb);
        const float qa = Q0, qb = Q1;

        const float cl1 = getf(buf, 3 * u + 3);
        const float o1  = getf(buf, 3 * u + 5);
        step(false, cl1, o1, Q0, Q1, l0, l1, al, tb);

        outp[u >> 1] = make_float4(qa, qb, Q0, Q1);  // (t,2) contiguous per row
    }
}

extern "C" __global__ void __launch_bounds__(64, 1)
uq_scan_kernel(const float* __restrict__ inp,
               const float* __restrict__ alpha0s,
               const float* __restrict__ gamma_alphas,
               const float* __restrict__ gamma_lams,
               const float* __restrict__ k_vals,
               float* __restrict__ out, int n_sess) {
    const int s = blockIdx.x * blockDim.x + threadIdx.x;
    if (s >= n_sess) return;

    Tables tb;
    tb.k0  = k_vals[0];       tb.k1  = k_vals[1];
    tb.k2  = k_vals[2];       tb.k3  = k_vals[3];
    tb.a00 = alpha0s[0];      tb.a01 = alpha0s[1];
    tb.a02 = alpha0s[2];      tb.a03 = alpha0s[3];
    tb.ga0 = gamma_alphas[0]; tb.ga1 = gamma_alphas[1];
    tb.ga2 = gamma_alphas[2]; tb.ga3 = gamma_alphas[3];
    tb.gl0 = gamma_lams[0];   tb.gl1 = gamma_lams[1];
    tb.gl2 = gamma_lams[2];   tb.gl3 = gamma_lams[3];

    const float4* __restrict__ rp =
        (const float4*)inp + (size_t)s * (N_TRIALS * 3 / 4);
    float4* __restrict__ op = (float4*)out + (size_t)s * (N_TRIALS * 2 / 4);

    float Q0 = 0.0f, Q1 = 0.0f, l0 = 0.5f, l1 = 0.5f, al = 0.0f;

    // Double-buffered register prefetch: 16 steps (192 B) per chunk.
    float4 cur[F4_IN], nxt[F4_IN];
#pragma unroll
    for (int i = 0; i < F4_IN; ++i) cur[i] = rp[i];

    for (int c = 0; c < NC; ++c) {
        const int pre = (c + 1 < NC) ? (c + 1) : c;  // last iter: harmless reload
#pragma unroll
        for (int i = 0; i < F4_IN; ++i) nxt[i] = rp[(size_t)pre * F4_IN + i];

        run_chunk(c == 0, cur, op + (size_t)c * F4_OUT, Q0, Q1, l0, l1, al, tb);

#pragma unroll
        for (int i = 0; i < F4_IN; ++i) cur[i] = nxt[i];
    }
}

extern "C" void kernel_launch(void* const* d_in, const int* in_sizes, int n_in,
                              void* d_out, int out_size, void* d_ws, size_t ws_size,
                              hipStream_t stream) {
    const float* inp = (const float*)d_in[0];
    const float* a0  = (const float*)d_in[1];
    const float* ga  = (const float*)d_in[2];
    const float* gl  = (const float*)d_in[3];
    const float* kv  = (const float*)d_in[4];
    float* out       = (float*)d_out;

    const int n_sess = in_sizes[0] / (N_TRIALS * 3);
    const int block  = 64;                 // 1 wave/block -> 128 blocks spread over CUs
    const int grid   = (n_sess + block - 1) / block;
    uq_scan_kernel<<<grid, block, 0, stream>>>(inp, a0, ga, gl, kv, out, n_sess);
}